// Round 6
// baseline (56.661 us; speedup 1.0000x reference)
//
#include <hip/hip_runtime.h>
#include <hip/hip_bf16.h>
#include <stdint.h>

// Problem geometry
#define NB 64          // batch
#define NC 64          // C_IN
#define NU 2048        // N_UNITS
#define K_REAL 1296    // H*W = 36*36
#define K_PAD  1408    // 4*352 = 4*11*32, zero-padded K (4-way split-K)
#define M_ROWS 4096    // NB*NC
#define NSPLIT 4
#define K_SPLIT 352    // per-split K extent
#define NKT_S (K_SPLIT / 32)   // 11 K-steps per split

// GEMM tile
#define BM 128
#define BN 128
#define BK 32

typedef __attribute__((ext_vector_type(4))) float f32x4;
typedef __attribute__((ext_vector_type(8))) short bf16x8;

__device__ __forceinline__ unsigned short f2bf_rne(float f) {
  union { float f; uint32_t u; } v; v.f = f;
  uint32_t u = v.u;
  return (unsigned short)((u + 0x7FFFu + ((u >> 16) & 1u)) >> 16);
}

// Convert fp32 [rows][K_REAL] -> bf16 [rows][K_PAD], zero-filling the pad
// tail. Handles BOTH x (rows 0..4095) and sw (rows 4096..6143) in one launch.
__global__ void convert_pad_kernel(const float* __restrict__ x,
                                   const float* __restrict__ sw,
                                   unsigned short* __restrict__ dst) {
  const int KB = K_PAD / 8;  // 176 8-element blocks per row
  const int total = (M_ROWS + NU) * KB;
  for (int idx = blockIdx.x * blockDim.x + threadIdx.x; idx < total;
       idx += gridDim.x * blockDim.x) {
    int r  = idx / KB;
    int kb = idx - r * KB;
    int k0 = kb * 8;
    uint32_t p0 = 0, p1 = 0, p2 = 0, p3 = 0;
    if (k0 + 8 <= K_REAL) {  // K_REAL % 8 == 0: blocks are all-real or all-pad
      const float* srow = (r < M_ROWS) ? (x + (size_t)r * K_REAL)
                                       : (sw + (size_t)(r - M_ROWS) * K_REAL);
      const float4* s = (const float4*)(srow + k0);
      float4 f0 = s[0];
      float4 f1 = s[1];
      p0 = (uint32_t)f2bf_rne(f0.x) | ((uint32_t)f2bf_rne(f0.y) << 16);
      p1 = (uint32_t)f2bf_rne(f0.z) | ((uint32_t)f2bf_rne(f0.w) << 16);
      p2 = (uint32_t)f2bf_rne(f1.x) | ((uint32_t)f2bf_rne(f1.y) << 16);
      p3 = (uint32_t)f2bf_rne(f1.z) | ((uint32_t)f2bf_rne(f1.w) << 16);
    }
    uint4 o; o.x = p0; o.y = p1; o.z = p2; o.w = p3;
    *(uint4*)(dst + (size_t)r * K_PAD + k0) = o;
  }
}

// Fused 4-way split-K GEMM (R1 structure: single-buffer, 2-phase, 16KB LDS —
// the 64-VGPR body — but at 8 blocks/CU available occupancy).
// G[(b,c),u] = sum_hw xbf[(b,c),hw] * swbf[u,hw]
// epilogue: part[split][b][u] = sum_c fw[u,c]*G_partial[(b,c),u]
// M-tile of 128 rows = 2 complete batches -> plain stores, no atomics.
__global__ __launch_bounds__(256)
void fused_readout_gemm(const unsigned short* __restrict__ Abf,  // [M_ROWS][K_PAD]
                        const unsigned short* __restrict__ Bbf,  // [NU][K_PAD]
                        const float* __restrict__ fw,            // [NU][NC]
                        float* __restrict__ part) {              // [NSPLIT][NB][NU]
  __shared__ unsigned short As[BM * BK];
  __shared__ unsigned short Bs[BN * BK];

  const int tid  = threadIdx.x;
  const int lane = tid & 63;
  const int w    = tid >> 6;
  const int wr   = w >> 1;      // 0..1: which 64-row half (which batch)
  const int wc   = w & 1;       // 0..1: which 64-col half
  const int g    = lane >> 4;   // k-group 0..3
  const int rl   = lane & 15;

  // XCD swizzle: 2048 blocks = 8 chunks of 256; chunk c -> XCD c.
  // Each chunk = half a split's tiles: A 16x(128x352x2)=1.4MB + B 1.4MB < L2.
  const int braw  = (int)blockIdx.x;
  const int bid   = (braw & 7) * 256 + (braw >> 3);
  const int split = bid >> 9;               // 0..3
  const int tileM = (bid >> 4) & 31;        // 0..31
  const int tileN = bid & 15;               // 0..15
  const int rowA0 = tileM * BM;
  const int colB0 = tileN * BN;
  const int kbase = split * K_SPLIT;

  // Staging: 512 chunks of 16B each for A and B; 256 threads x 2 issues.
  // LDS chunk swizzle: slot (row,kc) holds global chunk kc ^ ((row>>1)&3).
  const int ci0  = tid;
  const int ci1  = 256 + tid;
  const int row0 = ci0 >> 2, kc0 = ci0 & 3;
  const int row1 = ci1 >> 2, kc1 = ci1 & 3;
  const int kcg0 = kc0 ^ ((row0 >> 1) & 3);
  const int kcg1 = kc1 ^ ((row1 >> 1) & 3);
  const unsigned short* gA0 = Abf + (size_t)(rowA0 + row0) * K_PAD + kbase + kcg0 * 8;
  const unsigned short* gA1 = Abf + (size_t)(rowA0 + row1) * K_PAD + kbase + kcg1 * 8;
  const unsigned short* gB0 = Bbf + (size_t)(colB0 + row0) * K_PAD + kbase + kcg0 * 8;
  const unsigned short* gB1 = Bbf + (size_t)(colB0 + row1) * K_PAD + kbase + kcg1 * 8;

  f32x4 acc[4][4];
#pragma unroll
  for (int m = 0; m < 4; ++m)
#pragma unroll
    for (int n = 0; n < 4; ++n) acc[m][n] = (f32x4)0.f;

  const int swz_rd = (g ^ ((rl >> 1) & 3)) * 8;  // swizzled chunk offset (shorts)
  const int arow = (wr * 64 + rl) * BK;
  const int brow = (wc * 64 + rl) * BK;

  for (int kt = 0; kt < NKT_S; ++kt) {
    const int k0 = kt * BK;
    __builtin_amdgcn_global_load_lds(
        (const __attribute__((address_space(1))) unsigned int*)(const void*)(gA0 + k0),
        (__attribute__((address_space(3))) unsigned int*)(void*)(As + ci0 * 8),
        16, 0, 0);
    __builtin_amdgcn_global_load_lds(
        (const __attribute__((address_space(1))) unsigned int*)(const void*)(gA1 + k0),
        (__attribute__((address_space(3))) unsigned int*)(void*)(As + ci1 * 8),
        16, 0, 0);
    __builtin_amdgcn_global_load_lds(
        (const __attribute__((address_space(1))) unsigned int*)(const void*)(gB0 + k0),
        (__attribute__((address_space(3))) unsigned int*)(void*)(Bs + ci0 * 8),
        16, 0, 0);
    __builtin_amdgcn_global_load_lds(
        (const __attribute__((address_space(1))) unsigned int*)(const void*)(gB1 + k0),
        (__attribute__((address_space(3))) unsigned int*)(void*)(Bs + ci1 * 8),
        16, 0, 0);
    __syncthreads();

    bf16x8 a[4], b[4];
#pragma unroll
    for (int m = 0; m < 4; ++m)
      a[m] = *(const bf16x8*)(As + arow + m * 16 * BK + swz_rd);
#pragma unroll
    for (int n = 0; n < 4; ++n)
      b[n] = *(const bf16x8*)(Bs + brow + n * 16 * BK + swz_rd);
#pragma unroll
    for (int m = 0; m < 4; ++m)
#pragma unroll
      for (int n = 0; n < 4; ++n)
        acc[m][n] = __builtin_amdgcn_mfma_f32_16x16x32_bf16(a[m], b[n], acc[m][n], 0, 0, 0);

    __syncthreads();
  }

  // Epilogue: weighted reduction over the wave's 64 rows (= c of one batch).
  // acc[m][n] elem j = G(c = m*16+g*4+j, u = colB0+wc*64+n*16+rl).
  const int bidx = tileM * 2 + wr;
  float vtmp[4];
#pragma unroll
  for (int n = 0; n < 4; ++n) {
    const int u = colB0 + wc * 64 + n * 16 + rl;
    const float* fwrow = fw + (size_t)u * NC;
    float s = 0.f;
#pragma unroll
    for (int m = 0; m < 4; ++m) {
      float4 w4 = *(const float4*)(fwrow + m * 16 + g * 4);
      f32x4 av = acc[m][n];
      s += w4.x * av[0] + w4.y * av[1] + w4.z * av[2] + w4.w * av[3];
    }
    s += __shfl_xor(s, 16, 64);
    s += __shfl_xor(s, 32, 64);
    vtmp[n] = s;
  }

  const int ucol = colB0 + wc * 64 + lane;
  float r = (g == 0) ? vtmp[0] : (g == 1) ? vtmp[1] : (g == 2) ? vtmp[2] : vtmp[3];
  part[((size_t)split * NB + bidx) * NU + ucol] = r;
}

// out[b,u] = sum_s part[s][b][u] + bias[u]
__global__ __launch_bounds__(256)
void combine_kernel(const float* __restrict__ part,
                    const float* __restrict__ bias,
                    float* __restrict__ out) {
  int f = blockIdx.x * blockDim.x + threadIdx.x;  // float4 index, 0..32767
  const size_t plane = (size_t)NB * NU / 4;
  const float4* p = (const float4*)part;
  const float4* bz = (const float4*)bias;
  float4 a = p[f];
  float4 b = p[f + plane];
  float4 c = p[f + 2 * plane];
  float4 d = p[f + 3 * plane];
  float4 e = bz[f & 511];
  float4 o;
  o.x = a.x + b.x + c.x + d.x + e.x;
  o.y = a.y + b.y + c.y + d.y + e.y;
  o.z = a.z + b.z + c.z + d.z + e.z;
  o.w = a.w + b.w + c.w + d.w + e.w;
  ((float4*)out)[f] = o;
}

extern "C" void kernel_launch(void* const* d_in, const int* in_sizes, int n_in,
                              void* d_out, int out_size, void* d_ws, size_t ws_size,
                              hipStream_t stream) {
  const float* x    = (const float*)d_in[0];  // [64,64,36,36]
  const float* fw   = (const float*)d_in[1];  // [2048,64,1,1]
  const float* bias = (const float*)d_in[2];  // [2048]
  const float* sw   = (const float*)d_in[3];  // [2048,36,36]
  float* out = (float*)d_out;                 // [64][2048]

  unsigned short* Abf = (unsigned short*)d_ws;            // 4096*1408*2 B
  unsigned short* Bbf = Abf + (size_t)M_ROWS * K_PAD;     // 2048*1408*2 B
  float* part = (float*)(Bbf + (size_t)NU * K_PAD);       // 4*64*2048*4 B

  // Convert + zero-pad both inputs to bf16 (K-major), one launch
  {
    int total = (M_ROWS + NU) * (K_PAD / 8);
    int blocks = (total + 255) / 256;
    if (blocks > 2048) blocks = 2048;
    convert_pad_kernel<<<blocks, 256, 0, stream>>>(x, sw, Abf);
  }

  // Fused split-K GEMM + readout: 4 splits x 32 M-tiles x 16 N-tiles = 2048
  fused_readout_gemm<<<dim3(NSPLIT * 32 * 16), 256, 0, stream>>>(Abf, Bbf, fw, part);

  // Cross-split combine + bias
  combine_kernel<<<dim3((NB * NU / 4) / 256), 256, 0, stream>>>(part, bias, out);
}

// Round 7
// 52.061 us; speedup vs baseline: 1.0884x; 1.0884x over previous
//
#include <hip/hip_runtime.h>
#include <hip/hip_bf16.h>
#include <stdint.h>

// Problem geometry
#define NB 64          // batch
#define NC 64          // C_IN
#define NU 2048        // N_UNITS
#define K_REAL 1296    // H*W = 36*36
#define K_PAD  1408    // 4*352 = 4*11*32, zero-padded K (4-way split-K)
#define M_ROWS 4096    // NB*NC
#define NSPLIT 4
#define K_SPLIT 352    // per-split K extent
#define NKT_S (K_SPLIT / 32)   // 11 K-steps per split

// GEMM tile
#define BM 128
#define BN 128
#define BK 32

typedef __attribute__((ext_vector_type(4))) float f32x4;
typedef __attribute__((ext_vector_type(8))) short bf16x8;

__device__ __forceinline__ unsigned short f2bf_rne(float f) {
  union { float f; uint32_t u; } v; v.f = f;
  uint32_t u = v.u;
  return (unsigned short)((u + 0x7FFFu + ((u >> 16) & 1u)) >> 16);
}

// Convert fp32 [rows][K_REAL] -> bf16 [rows][K_PAD], zero-filling the pad
// tail. Handles BOTH x (rows 0..4095) and sw (rows 4096..6143) in one launch.
__global__ void convert_pad_kernel(const float* __restrict__ x,
                                   const float* __restrict__ sw,
                                   unsigned short* __restrict__ dst) {
  const int KB = K_PAD / 8;  // 176 8-element blocks per row
  const int total = (M_ROWS + NU) * KB;
  for (int idx = blockIdx.x * blockDim.x + threadIdx.x; idx < total;
       idx += gridDim.x * blockDim.x) {
    int r  = idx / KB;
    int kb = idx - r * KB;
    int k0 = kb * 8;
    uint32_t p0 = 0, p1 = 0, p2 = 0, p3 = 0;
    if (k0 + 8 <= K_REAL) {  // K_REAL % 8 == 0: blocks are all-real or all-pad
      const float* srow = (r < M_ROWS) ? (x + (size_t)r * K_REAL)
                                       : (sw + (size_t)(r - M_ROWS) * K_REAL);
      const float4* s = (const float4*)(srow + k0);
      float4 f0 = s[0];
      float4 f1 = s[1];
      p0 = (uint32_t)f2bf_rne(f0.x) | ((uint32_t)f2bf_rne(f0.y) << 16);
      p1 = (uint32_t)f2bf_rne(f0.z) | ((uint32_t)f2bf_rne(f0.w) << 16);
      p2 = (uint32_t)f2bf_rne(f1.x) | ((uint32_t)f2bf_rne(f1.y) << 16);
      p3 = (uint32_t)f2bf_rne(f1.z) | ((uint32_t)f2bf_rne(f1.w) << 16);
    }
    uint4 o; o.x = p0; o.y = p1; o.z = p2; o.w = p3;
    *(uint4*)(dst + (size_t)r * K_PAD + k0) = o;
  }
}

// Fused 4-way split-K GEMM (R1 2-phase structure, 16KB LDS).
// KEY CHANGE vs R6: __launch_bounds__(256, 4) forces total VGPR+AGPR <= 128
// (gfx950 unified file; acc[4][4] = 64 AGPR + body must fit 64 VGPR).
// At 132 total regs the HW occupancy quantum drops to 8 waves/CU (2 blocks);
// at <=128 we get 16 waves/CU (4 blocks) — 2x the latency-hiding TLP.
__global__ __launch_bounds__(256, 4)
void fused_readout_gemm(const unsigned short* __restrict__ Abf,  // [M_ROWS][K_PAD]
                        const unsigned short* __restrict__ Bbf,  // [NU][K_PAD]
                        const float* __restrict__ fw,            // [NU][NC]
                        float* __restrict__ part) {              // [NSPLIT][NB][NU]
  __shared__ unsigned short As[BM * BK];
  __shared__ unsigned short Bs[BN * BK];

  const int tid  = threadIdx.x;
  const int lane = tid & 63;
  const int w    = tid >> 6;
  const int wr   = w >> 1;      // 0..1: which 64-row half (which batch)
  const int wc   = w & 1;       // 0..1: which 64-col half
  const int g    = lane >> 4;   // k-group 0..3
  const int rl   = lane & 15;

  // XCD swizzle: 2048 blocks = 8 chunks of 256; chunk c -> XCD c.
  const int braw  = (int)blockIdx.x;
  const int bid   = (braw & 7) * 256 + (braw >> 3);
  const int split = bid >> 9;               // 0..3
  const int tileM = (bid >> 4) & 31;        // 0..31
  const int tileN = bid & 15;               // 0..15
  const int rowA0 = tileM * BM;
  const int colB0 = tileN * BN;
  const int kbase = split * K_SPLIT;

  // Staging: 512 chunks of 16B each for A and B; 256 threads x 2 issues.
  // LDS chunk swizzle: slot (row,kc) holds global chunk kc ^ ((row>>1)&3).
  const int ci0  = tid;
  const int ci1  = 256 + tid;
  const int row0 = ci0 >> 2, kc0 = ci0 & 3;
  const int row1 = ci1 >> 2, kc1 = ci1 & 3;
  const int kcg0 = kc0 ^ ((row0 >> 1) & 3);
  const int kcg1 = kc1 ^ ((row1 >> 1) & 3);
  const unsigned short* gA0 = Abf + (size_t)(rowA0 + row0) * K_PAD + kbase + kcg0 * 8;
  const unsigned short* gA1 = Abf + (size_t)(rowA0 + row1) * K_PAD + kbase + kcg1 * 8;
  const unsigned short* gB0 = Bbf + (size_t)(colB0 + row0) * K_PAD + kbase + kcg0 * 8;
  const unsigned short* gB1 = Bbf + (size_t)(colB0 + row1) * K_PAD + kbase + kcg1 * 8;

  f32x4 acc[4][4];
#pragma unroll
  for (int m = 0; m < 4; ++m)
#pragma unroll
    for (int n = 0; n < 4; ++n) acc[m][n] = (f32x4)0.f;

  const int swz_rd = (g ^ ((rl >> 1) & 3)) * 8;  // swizzled chunk offset (shorts)
  const int arow = (wr * 64 + rl) * BK;
  const int brow = (wc * 64 + rl) * BK;

  for (int kt = 0; kt < NKT_S; ++kt) {
    const int k0 = kt * BK;
    __builtin_amdgcn_global_load_lds(
        (const __attribute__((address_space(1))) unsigned int*)(const void*)(gA0 + k0),
        (__attribute__((address_space(3))) unsigned int*)(void*)(As + ci0 * 8),
        16, 0, 0);
    __builtin_amdgcn_global_load_lds(
        (const __attribute__((address_space(1))) unsigned int*)(const void*)(gA1 + k0),
        (__attribute__((address_space(3))) unsigned int*)(void*)(As + ci1 * 8),
        16, 0, 0);
    __builtin_amdgcn_global_load_lds(
        (const __attribute__((address_space(1))) unsigned int*)(const void*)(gB0 + k0),
        (__attribute__((address_space(3))) unsigned int*)(void*)(Bs + ci0 * 8),
        16, 0, 0);
    __builtin_amdgcn_global_load_lds(
        (const __attribute__((address_space(1))) unsigned int*)(const void*)(gB1 + k0),
        (__attribute__((address_space(3))) unsigned int*)(void*)(Bs + ci1 * 8),
        16, 0, 0);
    __syncthreads();

    bf16x8 a[4], b[4];
#pragma unroll
    for (int m = 0; m < 4; ++m)
      a[m] = *(const bf16x8*)(As + arow + m * 16 * BK + swz_rd);
#pragma unroll
    for (int n = 0; n < 4; ++n)
      b[n] = *(const bf16x8*)(Bs + brow + n * 16 * BK + swz_rd);
#pragma unroll
    for (int m = 0; m < 4; ++m)
#pragma unroll
      for (int n = 0; n < 4; ++n)
        acc[m][n] = __builtin_amdgcn_mfma_f32_16x16x32_bf16(a[m], b[n], acc[m][n], 0, 0, 0);

    __syncthreads();
  }

  // Epilogue: weighted reduction over the wave's 64 rows (= c of one batch).
  // acc[m][n] elem j = G(c = m*16+g*4+j, u = colB0+wc*64+n*16+rl).
  const int bidx = tileM * 2 + wr;
  float vtmp[4];
#pragma unroll
  for (int n = 0; n < 4; ++n) {
    const int u = colB0 + wc * 64 + n * 16 + rl;
    const float* fwrow = fw + (size_t)u * NC;
    float s = 0.f;
#pragma unroll
    for (int m = 0; m < 4; ++m) {
      float4 w4 = *(const float4*)(fwrow + m * 16 + g * 4);
      f32x4 av = acc[m][n];
      s += w4.x * av[0] + w4.y * av[1] + w4.z * av[2] + w4.w * av[3];
    }
    s += __shfl_xor(s, 16, 64);
    s += __shfl_xor(s, 32, 64);
    vtmp[n] = s;
  }

  const int ucol = colB0 + wc * 64 + lane;
  float r = (g == 0) ? vtmp[0] : (g == 1) ? vtmp[1] : (g == 2) ? vtmp[2] : vtmp[3];
  part[((size_t)split * NB + bidx) * NU + ucol] = r;
}

// out[b,u] = sum_s part[s][b][u] + bias[u]
__global__ __launch_bounds__(256)
void combine_kernel(const float* __restrict__ part,
                    const float* __restrict__ bias,
                    float* __restrict__ out) {
  int f = blockIdx.x * blockDim.x + threadIdx.x;  // float4 index, 0..32767
  const size_t plane = (size_t)NB * NU / 4;
  const float4* p = (const float4*)part;
  const float4* bz = (const float4*)bias;
  float4 a = p[f];
  float4 b = p[f + plane];
  float4 c = p[f + 2 * plane];
  float4 d = p[f + 3 * plane];
  float4 e = bz[f & 511];
  float4 o;
  o.x = a.x + b.x + c.x + d.x + e.x;
  o.y = a.y + b.y + c.y + d.y + e.y;
  o.z = a.z + b.z + c.z + d.z + e.z;
  o.w = a.w + b.w + c.w + d.w + e.w;
  ((float4*)out)[f] = o;
}

extern "C" void kernel_launch(void* const* d_in, const int* in_sizes, int n_in,
                              void* d_out, int out_size, void* d_ws, size_t ws_size,
                              hipStream_t stream) {
  const float* x    = (const float*)d_in[0];  // [64,64,36,36]
  const float* fw   = (const float*)d_in[1];  // [2048,64,1,1]
  const float* bias = (const float*)d_in[2];  // [2048]
  const float* sw   = (const float*)d_in[3];  // [2048,36,36]
  float* out = (float*)d_out;                 // [64][2048]

  unsigned short* Abf = (unsigned short*)d_ws;            // 4096*1408*2 B
  unsigned short* Bbf = Abf + (size_t)M_ROWS * K_PAD;     // 2048*1408*2 B
  float* part = (float*)(Bbf + (size_t)NU * K_PAD);       // 4*64*2048*4 B

  // Convert + zero-pad both inputs to bf16 (K-major), one launch
  {
    int total = (M_ROWS + NU) * (K_PAD / 8);
    int blocks = (total + 255) / 256;
    if (blocks > 2048) blocks = 2048;
    convert_pad_kernel<<<blocks, 256, 0, stream>>>(x, sw, Abf);
  }

  // Fused split-K GEMM + readout: 4 splits x 32 M-tiles x 16 N-tiles = 2048
  fused_readout_gemm<<<dim3(NSPLIT * 32 * 16), 256, 0, stream>>>(Abf, Bbf, fw, part);

  // Cross-split combine + bias
  combine_kernel<<<dim3((NB * NU / 4) / 256), 256, 0, stream>>>(part, bias, out);
}

// Round 8
// 42.611 us; speedup vs baseline: 1.3297x; 1.2218x over previous
//
#include <hip/hip_runtime.h>
#include <hip/hip_bf16.h>
#include <stdint.h>

// Problem geometry
#define NB 64          // batch
#define NC 64          // C_IN
#define NU 2048        // N_UNITS
#define K_REAL 1296    // H*W = 36*36
#define K_PAD  1344    // 21 K-tiles of 64 (3.7% pad)
#define M_ROWS 4096    // NB*NC

// GEMM tile
#define BM 256
#define BN 128

typedef __attribute__((ext_vector_type(4))) float f32x4;
typedef __attribute__((ext_vector_type(8))) short bf16x8;

__device__ __forceinline__ unsigned short f2bf_rne(float f) {
  union { float f; uint32_t u; } v; v.f = f;
  uint32_t u = v.u;
  return (unsigned short)((u + 0x7FFFu + ((u >> 16) & 1u)) >> 16);
}

// Convert fp32 [rows][K_REAL] -> bf16 [rows][K_PAD], zero-filling the pad
// tail. Handles BOTH x (rows 0..4095) and sw (rows 4096..6143) in one launch.
__global__ void convert_pad_kernel(const float* __restrict__ x,
                                   const float* __restrict__ sw,
                                   unsigned short* __restrict__ dst) {
  const int KB = K_PAD / 8;  // 168 8-element blocks per row
  const int total = (M_ROWS + NU) * KB;
  for (int idx = blockIdx.x * blockDim.x + threadIdx.x; idx < total;
       idx += gridDim.x * blockDim.x) {
    int r  = idx / KB;
    int kb = idx - r * KB;
    int k0 = kb * 8;
    uint32_t p0 = 0, p1 = 0, p2 = 0, p3 = 0;
    if (k0 + 8 <= K_REAL) {  // K_REAL % 8 == 0: blocks are all-real or all-pad
      const float* srow = (r < M_ROWS) ? (x + (size_t)r * K_REAL)
                                       : (sw + (size_t)(r - M_ROWS) * K_REAL);
      const float4* s = (const float4*)(srow + k0);
      float4 f0 = s[0];
      float4 f1 = s[1];
      p0 = (uint32_t)f2bf_rne(f0.x) | ((uint32_t)f2bf_rne(f0.y) << 16);
      p1 = (uint32_t)f2bf_rne(f0.z) | ((uint32_t)f2bf_rne(f0.w) << 16);
      p2 = (uint32_t)f2bf_rne(f1.x) | ((uint32_t)f2bf_rne(f1.y) << 16);
      p3 = (uint32_t)f2bf_rne(f1.z) | ((uint32_t)f2bf_rne(f1.w) << 16);
    }
    uint4 o; o.x = p0; o.y = p1; o.z = p2; o.w = p3;
    *(uint4*)(dst + (size_t)r * K_PAD + k0) = o;
  }
}

// ---------------------------------------------------------------------------
// 256x128 8-phase fused GEMM, split-K=1, 21 K-tiles of 64 (10 full iterations
// of 2 tiles + 1 tail tile). 8 waves = 4M x 2N; per wave 4x4 16x16x32 MFMA
// fragments (64 AGPR acc). LDS 96KB: A[buf][ks][256x32], B[buf][ks][128x32],
// tile t -> buf t&1, ks = 32-element K-halves.
// Swizzle (16B chunks, involution): phys chunk p holds logical p^((p>>3)&3);
// read addr byte = row*64 + (g*16 ^ (((rl>>1)&3)<<4)).  (0 conflicts, R5/R7.)
// Phase = { 8 ds_read frags | stage slot (3 gload_lds) -> BAR -> 16 MFMA
//           (setprio) -> vmcnt(6) -> BAR }.
// Stage schedule (iter it, tiles t0=2it,t1=2it+1):
//   A: read(buf0,k0), stage (t1,  k1)->buf1.k1  (last read prev-D, bar-safe)
//   B: read(buf0,k1), stage (t1+1,k0)->buf0.k0  (last read this-A)
//   C: read(buf1,k0), stage (t1+1,k1)->buf0.k1  (last read this-B)
//   D: read(buf1,k1), stage (t1+2,k0)->buf1.k0  (last read this-C)
// Every stage targets the plane whose reads completed one barrier earlier
// (lgkmcnt drained before MFMA before BAR2). vmcnt(6) = 2 slots in flight;
// stage->consume distance = 4 phases (~covers L2/L3 latency).
// ---------------------------------------------------------------------------
__global__ __launch_bounds__(512, 1)
void fused_readout_gemm(const unsigned short* __restrict__ Abf,  // [M_ROWS][K_PAD]
                        const unsigned short* __restrict__ Bbf,  // [NU][K_PAD]
                        const float* __restrict__ fw,            // [NU][NC]
                        const float* __restrict__ bias,          // [NU]
                        float* __restrict__ out) {               // [NB][NU]
  __shared__ unsigned short As[2][2][8192];  // [buf][ks][256 rows x 32]
  __shared__ unsigned short Bs[2][2][4096];  // [buf][ks][128 rows x 32]

  const int tid  = threadIdx.x;
  const int lane = tid & 63;
  const int w    = tid >> 6;    // 0..7
  const int wm   = w >> 1;      // 0..3: 64-row group (one batch each)
  const int wn   = w & 1;       // 0..1: 64-col group
  const int g    = lane >> 4;   // k-group 0..3
  const int rl   = lane & 15;

  // XCD swizzle: 256 blocks = 8 chunks of 32
  const int braw  = (int)blockIdx.x;
  const int bid   = (braw & 7) * 32 + (braw >> 3);
  const int tileM = bid >> 4;    // 0..15
  const int tileN = bid & 15;    // 0..15
  const int rowA0 = tileM * BM;
  const int colB0 = tileN * BN;

  // Pre-swizzled staging sources. Thread stages A phys chunks {tid, 512+tid}
  // and B phys chunk {tid}; logical chunk = p ^ ((p>>3)&3).
  const int lc  = tid ^ ((tid >> 3) & 3);
  const int sr  = lc >> 2;   // 0..127
  const int sc  = lc & 3;
  const unsigned short* srcA = Abf + (size_t)(rowA0 + sr) * K_PAD + sc * 8;
  const unsigned short* srcB = Bbf + (size_t)(colB0 + sr) * K_PAD + sc * 8;

  // Read-side byte offset within a ks-plane (swizzle folded in).
  const int laneOff = rl * 64 + ((g * 16) ^ (((rl >> 1) & 3) << 4));

#define GLOAD(dst, src)                                                         \
  __builtin_amdgcn_global_load_lds(                                             \
      (const __attribute__((address_space(1))) unsigned int*)(const void*)(src),\
      (__attribute__((address_space(3))) unsigned int*)(void*)(dst), 16, 0, 0)

  // Stage slot: one (tile, ks) pair = A half-plane (2 loads) + B half (1).
#define SLOT(buf, s, kk)                                                        \
  do {                                                                          \
    char* _pa = (char*)&As[buf][s][0];                                          \
    GLOAD(_pa + tid * 16, srcA + (kk));                                         \
    GLOAD(_pa + 8192 + tid * 16, srcA + (size_t)128 * K_PAD + (kk));            \
    GLOAD((char*)&Bs[buf][s][0] + tid * 16, srcB + (kk));                       \
  } while (0)

#define LDFRAGS(buf, ks)                                                        \
  do {                                                                          \
    const char* _pa = (const char*)&As[buf][ks][0] + wm * 4096 + laneOff;       \
    av[0] = *(const bf16x8*)(_pa);                                              \
    av[1] = *(const bf16x8*)(_pa + 1024);                                       \
    av[2] = *(const bf16x8*)(_pa + 2048);                                       \
    av[3] = *(const bf16x8*)(_pa + 3072);                                       \
    const char* _pb = (const char*)&Bs[buf][ks][0] + wn * 4096 + laneOff;       \
    bv[0] = *(const bf16x8*)(_pb);                                              \
    bv[1] = *(const bf16x8*)(_pb + 1024);                                       \
    bv[2] = *(const bf16x8*)(_pb + 2048);                                       \
    bv[3] = *(const bf16x8*)(_pb + 3072);                                       \
  } while (0)

#define MFMA16()                                                                \
  do {                                                                          \
    __builtin_amdgcn_s_setprio(1);                                              \
    _Pragma("unroll") for (int _m = 0; _m < 4; ++_m)                            \
      _Pragma("unroll") for (int _n = 0; _n < 4; ++_n)                          \
        acc[_m][_n] = __builtin_amdgcn_mfma_f32_16x16x32_bf16(                  \
            av[_m], bv[_n], acc[_m][_n], 0, 0, 0);                              \
    __builtin_amdgcn_s_setprio(0);                                              \
  } while (0)

#define BAR()                                                                   \
  do { __builtin_amdgcn_s_barrier(); __builtin_amdgcn_sched_barrier(0); } while (0)
#define VMW(N)                                                                  \
  do { asm volatile("s_waitcnt vmcnt(" #N ")" ::: "memory");                    \
       __builtin_amdgcn_sched_barrier(0); } while (0)

  f32x4 acc[4][4];
#pragma unroll
  for (int m = 0; m < 4; ++m)
#pragma unroll
    for (int n = 0; n < 4; ++n) acc[m][n] = (f32x4)0.f;

  bf16x8 av[4], bv[4];

  // Prologue: T0.k0, T0.k1, T1.k0 (9 loads); T0.k0 = oldest 3 -> vmcnt(6).
  SLOT(0, 0, 0);
  SLOT(0, 1, 32);
  SLOT(1, 0, 64);
  VMW(6); BAR();

#pragma unroll 1
  for (int it = 0; it < 9; ++it) {
    const int t1 = 2 * it + 1;
    // A: tiles t0.k0 | stage (t1,k1)
    LDFRAGS(0, 0); SLOT(1, 1, t1 * 64 + 32);       BAR(); MFMA16(); VMW(6); BAR();
    // B: t0.k1 | stage (t1+1,k0)
    LDFRAGS(0, 1); SLOT(0, 0, (t1 + 1) * 64);      BAR(); MFMA16(); VMW(6); BAR();
    // C: t1.k0 | stage (t1+1,k1)
    LDFRAGS(1, 0); SLOT(0, 1, (t1 + 1) * 64 + 32); BAR(); MFMA16(); VMW(6); BAR();
    // D: t1.k1 | stage (t1+2,k0)
    LDFRAGS(1, 1); SLOT(1, 0, (t1 + 2) * 64);      BAR(); MFMA16(); VMW(6); BAR();
  }
  // it9: tiles 18,19; stages 19.k1, 20.k0, 20.k1; drain starts.
  LDFRAGS(0, 0); SLOT(1, 1, 19 * 64 + 32); BAR(); MFMA16(); VMW(6); BAR();
  LDFRAGS(0, 1); SLOT(0, 0, 20 * 64);      BAR(); MFMA16(); VMW(6); BAR();
  LDFRAGS(1, 0); SLOT(0, 1, 20 * 64 + 32); BAR(); MFMA16(); VMW(6); BAR();
  LDFRAGS(1, 1);                           BAR(); MFMA16(); VMW(3); BAR();
  // tail: tile 20 (buf0)
  LDFRAGS(0, 0);                           BAR(); MFMA16(); VMW(0); BAR();
  LDFRAGS(0, 1);                           BAR(); MFMA16();

#undef GLOAD
#undef SLOT
#undef LDFRAGS
#undef MFMA16
#undef BAR
#undef VMW

  // Epilogue: wave's 64 rows = one batch (bidx = tileM*4 + wm).
  // acc[m][n] elem j = G(c = m*16 + g*4 + j, u = colB0 + wn*64 + n*16 + rl).
  const int bidx = tileM * 4 + wm;
  float vtmp[4];
#pragma unroll
  for (int n = 0; n < 4; ++n) {
    const int u = colB0 + wn * 64 + n * 16 + rl;
    const float* fwrow = fw + (size_t)u * NC;
    float s = 0.f;
#pragma unroll
    for (int m = 0; m < 4; ++m) {
      float4 w4 = *(const float4*)(fwrow + m * 16 + g * 4);
      f32x4 a_ = acc[m][n];
      s += w4.x * a_[0] + w4.y * a_[1] + w4.z * a_[2] + w4.w * a_[3];
    }
    s += __shfl_xor(s, 16, 64);   // reduce across k-groups (lanes ^16, ^32)
    s += __shfl_xor(s, 32, 64);
    vtmp[n] = s;
  }
  const int ucol = colB0 + wn * 64 + lane;
  float r = (g == 0) ? vtmp[0] : (g == 1) ? vtmp[1] : (g == 2) ? vtmp[2] : vtmp[3];
  out[(size_t)bidx * NU + ucol] = r + bias[ucol];
}

extern "C" void kernel_launch(void* const* d_in, const int* in_sizes, int n_in,
                              void* d_out, int out_size, void* d_ws, size_t ws_size,
                              hipStream_t stream) {
  const float* x    = (const float*)d_in[0];  // [64,64,36,36]
  const float* fw   = (const float*)d_in[1];  // [2048,64,1,1]
  const float* bias = (const float*)d_in[2];  // [2048]
  const float* sw   = (const float*)d_in[3];  // [2048,36,36]
  float* out = (float*)d_out;                 // [64][2048]

  unsigned short* Abf = (unsigned short*)d_ws;            // 4096*1344*2 B
  unsigned short* Bbf = Abf + (size_t)M_ROWS * K_PAD;     // 2048*1344*2 B

  // Convert + zero-pad both inputs to bf16 (K-major), one launch
  {
    int total = (M_ROWS + NU) * (K_PAD / 8);
    int blocks = (total + 255) / 256;
    if (blocks > 2048) blocks = 2048;
    convert_pad_kernel<<<blocks, 256, 0, stream>>>(x, sw, Abf);
  }

  // Fused GEMM + readout + bias: 16 M-tiles x 16 N-tiles = 256 blocks
  fused_readout_gemm<<<dim3(256), 512, 0, stream>>>(Abf, Bbf, fw, bias, out);
}

// Round 9
// 42.244 us; speedup vs baseline: 1.3413x; 1.0087x over previous
//
#include <hip/hip_runtime.h>
#include <hip/hip_bf16.h>
#include <stdint.h>

// Problem geometry
#define NB 64          // batch
#define NC 64          // C_IN
#define NU 2048        // N_UNITS
#define K_REAL 1296    // H*W = 36*36
#define K_PAD  1344    // 42 ks-steps of 32 (3.7% pad)
#define M_ROWS 4096    // NB*NC

// GEMM tile
#define BM 256
#define BN 128
#define NKS 42         // 32-wide K-steps

typedef __attribute__((ext_vector_type(4))) float f32x4;
typedef __attribute__((ext_vector_type(8))) short bf16x8;

__device__ __forceinline__ unsigned short f2bf_rne(float f) {
  union { float f; uint32_t u; } v; v.f = f;
  uint32_t u = v.u;
  return (unsigned short)((u + 0x7FFFu + ((u >> 16) & 1u)) >> 16);
}

// Convert fp32 [rows][K_REAL] -> bf16 [rows][K_PAD], zero-filling the pad
// tail. Handles BOTH x (rows 0..4095) and sw (rows 4096..6143) in one launch.
__global__ void convert_pad_kernel(const float* __restrict__ x,
                                   const float* __restrict__ sw,
                                   unsigned short* __restrict__ dst) {
  const int KB = K_PAD / 8;  // 168 8-element blocks per row
  const int total = (M_ROWS + NU) * KB;
  for (int idx = blockIdx.x * blockDim.x + threadIdx.x; idx < total;
       idx += gridDim.x * blockDim.x) {
    int r  = idx / KB;
    int kb = idx - r * KB;
    int k0 = kb * 8;
    uint32_t p0 = 0, p1 = 0, p2 = 0, p3 = 0;
    if (k0 + 8 <= K_REAL) {  // K_REAL % 8 == 0: blocks are all-real or all-pad
      const float* srow = (r < M_ROWS) ? (x + (size_t)r * K_REAL)
                                       : (sw + (size_t)(r - M_ROWS) * K_REAL);
      const float4* s = (const float4*)(srow + k0);
      float4 f0 = s[0];
      float4 f1 = s[1];
      p0 = (uint32_t)f2bf_rne(f0.x) | ((uint32_t)f2bf_rne(f0.y) << 16);
      p1 = (uint32_t)f2bf_rne(f0.z) | ((uint32_t)f2bf_rne(f0.w) << 16);
      p2 = (uint32_t)f2bf_rne(f1.x) | ((uint32_t)f2bf_rne(f1.y) << 16);
      p3 = (uint32_t)f2bf_rne(f1.z) | ((uint32_t)f2bf_rne(f1.w) << 16);
    }
    uint4 o; o.x = p0; o.y = p1; o.z = p2; o.w = p3;
    *(uint4*)(dst + (size_t)r * K_PAD + k0) = o;
  }
}

// ---------------------------------------------------------------------------
// 256x128 fused GEMM, ring-of-5 ks-slot pipeline (deepened R8).
// 8 waves = 4M x 2N; per wave 4x4 16x16x32 MFMA frags (64 AGPR acc).
// LDS 120KB: 5 slots, each one 32-wide K-step: A[256x32] (16KB) + B[128x32]
// (8KB). Slot(s) = s % 5. Phase s: { ds_read frags of slot s | stage ks s+4
// into slot (s+4)%5 -> BAR -> 16 MFMA (setprio) -> vmcnt(9) -> BAR }.
// vmcnt(9) = 3 slots (9 loads) in flight; slot staged 4 phases before read.
// Overwrite-safety: slot (s+4)%5 == (s-1)%5 was last READ in phase s-1; all
// waves' reads completed before the phase-(s-1) closing barrier (lgkmcnt
// drained before their MFMAs), and the stage is issued after that barrier.
// Tail (no stage after phase 37): VMW 9,9,9,6,3,0 then final MFMA.
// Swizzle (16B chunks, involution): phys chunk p holds logical p^((p>>3)&3);
// read addr byte = row*64 + (g*16 ^ (((rl>>1)&3)<<4)).  (0 conflicts, R5-R8.)
// XCD mapping: 4 tileM x 8 tileN rectangle per XCD -> per-XCD L2 working set
// 4x0.69 + 8x0.34 = 5.5 MB (was 6.9 with 2x16 chunks).
// ---------------------------------------------------------------------------
__global__ __launch_bounds__(512, 1)
void fused_readout_gemm(const unsigned short* __restrict__ Abf,  // [M_ROWS][K_PAD]
                        const unsigned short* __restrict__ Bbf,  // [NU][K_PAD]
                        const float* __restrict__ fw,            // [NU][NC]
                        const float* __restrict__ bias,          // [NU]
                        float* __restrict__ out) {               // [NB][NU]
  __shared__ unsigned short As[5][8192];  // slot: 256 rows x 32 (16KB)
  __shared__ unsigned short Bs[5][4096];  // slot: 128 rows x 32 (8KB)

  const int tid  = threadIdx.x;
  const int lane = tid & 63;
  const int w    = tid >> 6;    // 0..7
  const int wm   = w >> 1;      // 0..3: 64-row group (one batch each)
  const int wn   = w & 1;       // 0..1: 64-col group
  const int g    = lane >> 4;   // k-group 0..3
  const int rl   = lane & 15;

  // XCD mapping: xcd = braw&7 owns a 4(tileM) x 8(tileN) rectangle.
  const int braw  = (int)blockIdx.x;
  const int xcd   = braw & 7;
  const int idx   = braw >> 3;           // 0..31
  const int tileM = (xcd >> 1) * 4 + (idx & 3);
  const int tileN = (xcd & 1) * 8 + (idx >> 2);
  const int rowA0 = tileM * BM;
  const int colB0 = tileN * BN;

  // Pre-swizzled staging sources. Thread stages A phys chunks {tid, 512+tid}
  // and B phys chunk {tid}; logical chunk = p ^ ((p>>3)&3) (second A half has
  // the same XOR since 512 == 0 mod (8*4)).
  const int lc  = tid ^ ((tid >> 3) & 3);
  const int sr  = lc >> 2;   // 0..127
  const int sc  = lc & 3;
  const unsigned short* srcA = Abf + (size_t)(rowA0 + sr) * K_PAD + sc * 8;
  const unsigned short* srcB = Bbf + (size_t)(colB0 + sr) * K_PAD + sc * 8;

  // Read-side byte offset within a slot plane (swizzle folded in).
  const int laneOff = rl * 64 + ((g * 16) ^ (((rl >> 1) & 3) << 4));

#define GLOAD(dst, src)                                                         \
  __builtin_amdgcn_global_load_lds(                                             \
      (const __attribute__((address_space(1))) unsigned int*)(const void*)(src),\
      (__attribute__((address_space(3))) unsigned int*)(void*)(dst), 16, 0, 0)

  // Stage one ks-step (elements [koff, koff+32) of K) into slot j.
#define SLOT(j, koff)                                                           \
  do {                                                                          \
    char* _pa = (char*)&As[j][0];                                               \
    GLOAD(_pa + tid * 16, srcA + (koff));                                       \
    GLOAD(_pa + 8192 + tid * 16, srcA + (size_t)128 * K_PAD + (koff));          \
    GLOAD((char*)&Bs[j][0] + tid * 16, srcB + (koff));                          \
  } while (0)

#define LDFRAGS(j)                                                              \
  do {                                                                          \
    const char* _pa = (const char*)&As[j][0] + wm * 4096 + laneOff;             \
    av[0] = *(const bf16x8*)(_pa);                                              \
    av[1] = *(const bf16x8*)(_pa + 1024);                                       \
    av[2] = *(const bf16x8*)(_pa + 2048);                                       \
    av[3] = *(const bf16x8*)(_pa + 3072);                                       \
    const char* _pb = (const char*)&Bs[j][0] + wn * 4096 + laneOff;             \
    bv[0] = *(const bf16x8*)(_pb);                                              \
    bv[1] = *(const bf16x8*)(_pb + 1024);                                       \
    bv[2] = *(const bf16x8*)(_pb + 2048);                                       \
    bv[3] = *(const bf16x8*)(_pb + 3072);                                       \
  } while (0)

#define MFMA16()                                                                \
  do {                                                                          \
    __builtin_amdgcn_s_setprio(1);                                              \
    _Pragma("unroll") for (int _m = 0; _m < 4; ++_m)                            \
      _Pragma("unroll") for (int _n = 0; _n < 4; ++_n)                          \
        acc[_m][_n] = __builtin_amdgcn_mfma_f32_16x16x32_bf16(                  \
            av[_m], bv[_n], acc[_m][_n], 0, 0, 0);                              \
    __builtin_amdgcn_s_setprio(0);                                              \
  } while (0)

#define BAR()                                                                   \
  do { __builtin_amdgcn_s_barrier(); __builtin_amdgcn_sched_barrier(0); } while (0)
#define VMW(N)                                                                  \
  do { asm volatile("s_waitcnt vmcnt(" #N ")" ::: "memory");                    \
       __builtin_amdgcn_sched_barrier(0); } while (0)

  f32x4 acc[4][4];
#pragma unroll
  for (int m = 0; m < 4; ++m)
#pragma unroll
    for (int n = 0; n < 4; ++n) acc[m][n] = (f32x4)0.f;

  bf16x8 av[4], bv[4];

  // Prologue: slots 0..3 <- ks 0..3 (12 loads); wait for ks0 (oldest 3).
  SLOT(0, 0); SLOT(1, 32); SLOT(2, 64); SLOT(3, 96);
  VMW(9); BAR();

  int kb = 128;   // element offset of ks (s+4) when s = it*5
#pragma unroll 1
  for (int it = 0; it < 7; ++it) {   // phases s = it*5 .. it*5+4  (s = 0..34)
    LDFRAGS(0); SLOT(4, kb);       BAR(); MFMA16(); VMW(9); BAR();
    LDFRAGS(1); SLOT(0, kb + 32);  BAR(); MFMA16(); VMW(9); BAR();
    LDFRAGS(2); SLOT(1, kb + 64);  BAR(); MFMA16(); VMW(9); BAR();
    LDFRAGS(3); SLOT(2, kb + 96);  BAR(); MFMA16(); VMW(9); BAR();
    LDFRAGS(4); SLOT(3, kb + 128); BAR(); MFMA16(); VMW(9); BAR();
    kb += 160;
  }
  // Tail: s = 35..41 (kb == 1248 == ks39*32)
  LDFRAGS(0); SLOT(4, 1248); BAR(); MFMA16(); VMW(9); BAR();  // s=35 stage ks39
  LDFRAGS(1); SLOT(0, 1280); BAR(); MFMA16(); VMW(9); BAR();  // s=36 stage ks40
  LDFRAGS(2); SLOT(1, 1312); BAR(); MFMA16(); VMW(9); BAR();  // s=37 stage ks41
  LDFRAGS(3);                BAR(); MFMA16(); VMW(6); BAR();  // s=38
  LDFRAGS(4);                BAR(); MFMA16(); VMW(3); BAR();  // s=39
  LDFRAGS(0);                BAR(); MFMA16(); VMW(0); BAR();  // s=40 (ks40)
  LDFRAGS(1);                BAR(); MFMA16();                 // s=41 (ks41)

#undef GLOAD
#undef SLOT
#undef LDFRAGS
#undef MFMA16
#undef BAR
#undef VMW

  // Epilogue: wave's 64 rows = one batch (bidx = tileM*4 + wm).
  // acc[m][n] elem j = G(c = m*16 + g*4 + j, u = colB0 + wn*64 + n*16 + rl).
  const int bidx = tileM * 4 + wm;
  float vtmp[4];
#pragma unroll
  for (int n = 0; n < 4; ++n) {
    const int u = colB0 + wn * 64 + n * 16 + rl;
    const float* fwrow = fw + (size_t)u * NC;
    float s = 0.f;
#pragma unroll
    for (int m = 0; m < 4; ++m) {
      float4 w4 = *(const float4*)(fwrow + m * 16 + g * 4);
      f32x4 a_ = acc[m][n];
      s += w4.x * a_[0] + w4.y * a_[1] + w4.z * a_[2] + w4.w * a_[3];
    }
    s += __shfl_xor(s, 16, 64);   // reduce across k-groups (lanes ^16, ^32)
    s += __shfl_xor(s, 32, 64);
    vtmp[n] = s;
  }
  const int ucol = colB0 + wn * 64 + lane;
  float r = (g == 0) ? vtmp[0] : (g == 1) ? vtmp[1] : (g == 2) ? vtmp[2] : vtmp[3];
  out[(size_t)bidx * NU + ucol] = r + bias[ucol];
}

extern "C" void kernel_launch(void* const* d_in, const int* in_sizes, int n_in,
                              void* d_out, int out_size, void* d_ws, size_t ws_size,
                              hipStream_t stream) {
  const float* x    = (const float*)d_in[0];  // [64,64,36,36]
  const float* fw   = (const float*)d_in[1];  // [2048,64,1,1]
  const float* bias = (const float*)d_in[2];  // [2048]
  const float* sw   = (const float*)d_in[3];  // [2048,36,36]
  float* out = (float*)d_out;                 // [64][2048]

  unsigned short* Abf = (unsigned short*)d_ws;            // 4096*1344*2 B
  unsigned short* Bbf = Abf + (size_t)M_ROWS * K_PAD;     // 2048*1344*2 B

  // Convert + zero-pad both inputs to bf16 (K-major), one launch
  {
    int total = (M_ROWS + NU) * (K_PAD / 8);
    int blocks = (total + 255) / 256;
    if (blocks > 2048) blocks = 2048;
    convert_pad_kernel<<<blocks, 256, 0, stream>>>(x, sw, Abf);
  }

  // Fused GEMM + readout + bias: 16 M-tiles x 16 N-tiles = 256 blocks
  fused_readout_gemm<<<dim3(256), 512, 0, stream>>>(Abf, Bbf, fw, bias, out);
}